// Round 14
// baseline (135.821 us; speedup 1.0000x reference)
//
#include <hip/hip_runtime.h>

#define EGO 0.018315638888734179f   // exp(-4)
#define EGE 0.36787944117144233f    // exp(-1)

typedef float vf2 __attribute__((ext_vector_type(2)));

__device__ __forceinline__ vf2 pk_fma(vf2 a, vf2 b, vf2 c) {
  vf2 d; asm("v_pk_fma_f32 %0, %1, %2, %3" : "=v"(d) : "v"(a), "v"(b), "v"(c)); return d;
}
__device__ __forceinline__ vf2 pk_add(vf2 a, vf2 b) {
  vf2 d; asm("v_pk_add_f32 %0, %1, %2" : "=v"(d) : "v"(a), "v"(b)); return d;
}
__device__ __forceinline__ vf2 pk_mul(vf2 a, vf2 b) {
  vf2 d; asm("v_pk_mul_f32 %0, %1, %2" : "=v"(d) : "v"(a), "v"(b)); return d;
}

// DPP wave-wide shifts (GFX9/CDNA keep these; VALU latency, no LDS pipe).
// WAVE_SHR1 (0x138): lane i <- lane i-1 (lane 0 -> 0 with bound_ctrl).
// WAVE_SHL1 (0x130): lane i <- lane i+1 (lane 63 -> 0 with bound_ctrl).
__device__ __forceinline__ float dpp_shr1(float x) {
  return __int_as_float(__builtin_amdgcn_update_dpp(
      0, __float_as_int(x), 0x138, 0xf, 0xf, true));
}
__device__ __forceinline__ float dpp_shl1(float x) {
  return __int_as_float(__builtin_amdgcn_update_dpp(
      0, __float_as_int(x), 0x130, 0xf, 0xf, true));
}

__device__ __forceinline__ float escale(int k) {   // 2^k, clamped to normal range
  k = k < -126 ? -126 : (k > 127 ? 127 : k);
  return __uint_as_float((unsigned)(k + 127) << 23);
}

// =====================================================================
// Precompute diag-major gathered exp(scores), fp32:
// X[((b*512+p)*2+half)*512 + j]. Batch b's blocks land on XCD b%8 — the
// same XCD the DP block b (32 blocks, round-robin) will run on.
// =====================================================================
__global__ __launch_bounds__(512) void sw_pre_kernel(const float* __restrict__ pred,
                                                     const int* __restrict__ tgt,
                                                     float* __restrict__ X) {
  const int q = (int)blockIdx.x;
  const int b = (q & 7) | ((q >> 12) << 3);   // b%8 == q%8 -> XCD affinity
  const int p = (q >> 3) & 511;
  const int j = (int)threadIdx.x;
  const int a = 255 - j + p;
  const int c = p + j - 255;
  const bool av = (a >= 0) && (a < 512);
  float evn = 0.0f, odd = 0.0f;
  if (av && c >= 0 && c < 512)
    evn = __expf(pred[(((b << 9) + a) << 2) + tgt[(b << 9) + c]]);
  if (av && (c + 1) >= 0 && (c + 1) < 512)
    odd = __expf(pred[(((b << 9) + a) << 2) + tgt[(b << 9) + c + 1]]);
  float* base = X + (((size_t)((b << 9) | p)) << 10);
  base[j] = evn;
  base[512 + j] = odd;
}

// =====================================================================
// DP with halo: one batch/block, 8 waves, 2 slots/lane, packed fp32 math.
// vs R13: the two per-iteration lane rotations are DPP wave shifts
// (VALU latency) instead of ds_bpermute (~120cy LDS pipe). DPP edge lanes
// get 0 — feeds only halo fringe, wiped at the 32-iter refresh.
// =====================================================================
__global__ __launch_bounds__(512) void sw_dp_fast(const float* __restrict__ X,
                                                  float* __restrict__ partials) {
  __shared__ float SLDS[5 * 512];
  __shared__ float MXl[8], SUMl[8];
  __shared__ int   ETl[8], ETf[8];

  const int tid = (int)threadIdx.x;
  const int w = tid >> 6, lane = tid & 63;
  const int b = (int)blockIdx.x;
  const float* Xb = X + ((size_t)b << 19);
  const int jld = 64 * w - 32 + 2 * lane;

  int jj[2], PEes[2], POes[2];
  bool wrS[2], rdh[2], phh[2], owS[2];
  #pragma unroll
  for (int s = 0; s < 2; ++s) {
    const int j = jld + s;
    jj[s] = j;
    const bool vj = (j >= 0) && (j < 512);
    const int pe = (255 + j < 765 - j) ? 255 + j : 765 - j;
    const int po = (255 + j < 764 - j) ? 255 + j : 764 - j;
    PEes[s] = vj ? pe : -1;        // phantom slots: always gated off
    POes[s] = vj ? po : -1;
    owS[s] = (j >= 64 * w) && (j < 64 * w + 64);
    const int idx = 2 * lane + s;
    wrS[s] = (idx >= 32) && (idx < 96);
    const bool halo = (idx < 32) || (idx >= 96);
    rdh[s] = halo && vj;
    phh[s] = halo && !vj;
  }
  const bool isPh1 = (jj[1] == 511);    // wave 7, lane 47: kill its DC

  const vf2 EGOP = {EGO, EGO};
  const vf2 EGEP = {EGE, EGE};
  vf2 U = {0,0}, Dd = {0,0}, RC = {0,0}, SE = {0,0}, SO = {0,0}, acc = {0,0};
  vf2 oneP = {1.0f, 1.0f};
  int EtotW = 0;

  vf2 evb[4], odb[4];

#define LOADP(par, p) do {                                                    \
    const float* row_ = Xb + (((size_t)(p)) << 10);                           \
    evb[par] = *(const vf2*)(row_ + jld);                                     \
    odb[par] = *(const vf2*)(row_ + 512 + jld);                               \
  } while (0)

#define SYNC() do {                                                           \
    asm volatile("s_waitcnt lgkmcnt(0)" ::: "memory");                        \
    __builtin_amdgcn_s_barrier();                                             \
    asm volatile("" ::: "memory");                                            \
  } while (0)

#define ITER(par, nxt, p) do {                                                \
    /* ---- even substep (d=2p): right from slot-1 ---- */                    \
    const float rcS_ = dpp_shr1(RC.y);                                        \
    vf2 rightP; rightP.x = rcS_; rightP.y = RC.x;                             \
    vf2 dnP = pk_fma(U, EGOP, pk_mul(Dd, EGEP));                              \
    vf2 SEone = pk_add(SE, oneP);                                             \
    vf2 esgP;                                                                 \
    esgP.x = ((p) <= PEes[0]) ? evb[par].x : 0.0f;                            \
    esgP.y = ((p) <= PEes[1]) ? evb[par].y : 0.0f;                            \
    vf2 alP = pk_mul(esgP, SEone);                                            \
    vf2 UnP = pk_add(alP, rightP);                                            \
    vf2 s3P = pk_add(UnP, dnP);                                               \
    acc = pk_fma(s3P, evb[nxt], acc);                                         \
    SE = s3P;                                                                 \
    vf2 DCt = pk_fma(UnP, EGOP, pk_mul(dnP, EGEP));                           \
    if (isPh1) DCt.y = 0.0f;   /* slot 511 phantom must not leak */           \
    vf2 RCe = pk_fma(alP, EGOP, pk_mul(rightP, EGEP));                        \
    /* ---- odd substep (d=2p+1): down from slot+1 ---- */                    \
    const float dcS_ = dpp_shl1(DCt.x);                                       \
    vf2 dnvP; dnvP.x = DCt.y; dnvP.y = dcS_;                                  \
    vf2 SOone = pk_add(SO, oneP);                                             \
    vf2 esgO;                                                                 \
    esgO.x = ((p) <= POes[0]) ? odb[par].x : 0.0f;                            \
    esgO.y = ((p) <= POes[1]) ? odb[par].y : 0.0f;                            \
    vf2 alO = pk_mul(esgO, SOone);                                            \
    vf2 UnO = pk_add(alO, RCe);                                               \
    vf2 s3O = pk_add(UnO, dnvP);                                              \
    acc = pk_fma(s3O, odb[nxt], acc);                                         \
    SO = s3O;                                                                 \
    RC = pk_fma(alO, EGOP, pk_mul(RCe, EGEP));                                \
    U = UnO; Dd = dnvP;                                                       \
  } while (0)

#define SOLO() do {                                                           \
    float mxl = fmaxf(fmaxf(SE.x, SO.x), fmaxf(SE.y, SO.y));                  \
    _Pragma("unroll")                                                         \
    for (int off = 1; off < 64; off <<= 1) mxl = fmaxf(mxl, __shfl_xor(mxl, off, 64)); \
    const int ex = (int)((__float_as_uint(mxl) >> 23) & 0xff);                \
    if (ex > 0) {                                                             \
      const float sc = __uint_as_float((unsigned)(253 - ex) << 23);           \
      EtotW += ex - 126;                                                      \
      vf2 scP = {sc, sc};                                                     \
      U = pk_mul(U, scP); Dd = pk_mul(Dd, scP); RC = pk_mul(RC, scP);         \
      SE = pk_mul(SE, scP); SO = pk_mul(SO, scP); acc = pk_mul(acc, scP);     \
      oneP = pk_mul(oneP, scP);                                               \
    }                                                                         \
  } while (0)

#define REFRESH() do {                                                        \
    float mxl = fmaxf(owS[0] ? fmaxf(SE.x, SO.x) : 0.0f,                      \
                      owS[1] ? fmaxf(SE.y, SO.y) : 0.0f);                     \
    _Pragma("unroll")                                                         \
    for (int off = 1; off < 64; off <<= 1) mxl = fmaxf(mxl, __shfl_xor(mxl, off, 64)); \
    if (lane == 0) { MXl[w] = mxl; ETl[w] = EtotW; }                          \
    if (wrS[0]) {                                                             \
      SLDS[jj[0]] = U.x; SLDS[512 + jj[0]] = Dd.x; SLDS[1024 + jj[0]] = RC.x; \
      SLDS[1536 + jj[0]] = SE.x; SLDS[2048 + jj[0]] = SO.x;                   \
    }                                                                         \
    if (wrS[1]) {                                                             \
      SLDS[jj[1]] = U.y; SLDS[512 + jj[1]] = Dd.y; SLDS[1024 + jj[1]] = RC.y; \
      SLDS[1536 + jj[1]] = SE.y; SLDS[2048 + jj[1]] = SO.y;                   \
    }                                                                         \
    SYNC();                                                                   \
    int ets_[8]; float mxs_[8];                                               \
    _Pragma("unroll")                                                         \
    for (int q2 = 0; q2 < 8; ++q2) { mxs_[q2] = MXl[q2]; ets_[q2] = ETl[q2]; }\
    int tn_ = -2147483647;                                                    \
    _Pragma("unroll")                                                         \
    for (int q2 = 0; q2 < 8; ++q2) {                                          \
      if (mxs_[q2] > 0.0f) {                                                  \
        const int t2_ = ets_[q2] + (int)((__float_as_uint(mxs_[q2]) >> 23) & 0xff) - 126; \
        if (t2_ > tn_) tn_ = t2_;                                             \
      }                                                                       \
    }                                                                         \
    if (tn_ == -2147483647) tn_ = EtotW;                                      \
    { const int dd_ = EtotW - tn_;                                            \
      const float ff_ = escale(dd_ - dd_ / 2) * escale(dd_ / 2);              \
      vf2 fP = {ff_, ff_};                                                    \
      U = pk_mul(U, fP); Dd = pk_mul(Dd, fP); RC = pk_mul(RC, fP);            \
      SE = pk_mul(SE, fP); SO = pk_mul(SO, fP); acc = pk_mul(acc, fP);        \
      oneP = pk_mul(oneP, fP); EtotW = tn_;                                   \
    }                                                                         \
    if (rdh[0]) {                                                             \
      const int oww_ = (2 * lane < 32) ? (w - 1) : (w + 1);                   \
      const int dd2_ = ets_[oww_] - EtotW;                                    \
      const float g_ = escale(dd2_ - dd2_ / 2) * escale(dd2_ / 2);            \
      U.x = SLDS[jj[0]] * g_; Dd.x = SLDS[512 + jj[0]] * g_;                  \
      RC.x = SLDS[1024 + jj[0]] * g_; SE.x = SLDS[1536 + jj[0]] * g_;         \
      SO.x = SLDS[2048 + jj[0]] * g_;                                         \
    } else if (phh[0]) { U.x = Dd.x = RC.x = SE.x = SO.x = 0.0f; }            \
    if (rdh[1]) {                                                             \
      const int oww_ = (2 * lane + 1 < 32) ? (w - 1) : (w + 1);               \
      const int dd2_ = ets_[oww_] - EtotW;                                    \
      const float g_ = escale(dd2_ - dd2_ / 2) * escale(dd2_ / 2);            \
      U.y = SLDS[jj[1]] * g_; Dd.y = SLDS[512 + jj[1]] * g_;                  \
      RC.y = SLDS[1024 + jj[1]] * g_; SE.y = SLDS[1536 + jj[1]] * g_;         \
      SO.y = SLDS[2048 + jj[1]] * g_;                                         \
    } else if (phh[1]) { U.y = Dd.y = RC.y = SE.y = SO.y = 0.0f; }            \
    SYNC();                                                                   \
  } while (0)

  LOADP(0, 0); LOADP(1, 1); LOADP(2, 2); LOADP(3, 3);

  for (int qq = 0; qq < 127; ++qq) {
    const int p0 = qq << 2;
    ITER(0, 1, p0);     LOADP(0, p0 + 4);
    ITER(1, 2, p0 + 1); LOADP(1, p0 + 5);
    ITER(2, 3, p0 + 2); LOADP(2, p0 + 6);
    ITER(3, 0, p0 + 3); LOADP(3, p0 + 7);
    const int ph = qq & 7;
    if (ph == 3) SOLO();
    else if (ph == 7) REFRESH();
  }
  // tail: p = 508, 509, 510 (buffers hold 508..511; pa reads 509..511)
  ITER(0, 1, 508); ITER(1, 2, 509); ITER(2, 3, 510);

  // owned-slot acc only (halo slots computed real values redundantly)
  float atot = (owS[0] ? acc.x : 0.0f) + (owS[1] ? acc.y : 0.0f);
  #pragma unroll
  for (int off = 1; off < 64; off <<= 1) atot += __shfl_xor(atot, off, 64);
  if (lane == 0) { SUMl[w] = atot; ETf[w] = EtotW; }
  __syncthreads();
  if (tid == 0) {
    int M = ETf[0];
    for (int q2 = 1; q2 < 8; ++q2) if (ETf[q2] > M) M = ETf[q2];
    float T = 0.0f;
    for (int q2 = 0; q2 < 8; ++q2) T += SUMl[q2] * escale(ETf[q2] - M);
    partials[b] = __logf(T) + (float)M * 0.69314718055994531f;
  }

#undef LOADP
#undef SYNC
#undef ITER
#undef SOLO
#undef REFRESH
}

// =====================================================================
// Fallback (R3, validated absmax 0.0): used when ws_size is too small.
// =====================================================================
__global__ __launch_bounds__(64) void sw_dp_kernel(const float* __restrict__ pred,
                                                   const int* __restrict__ tgt,
                                                   float* __restrict__ partials) {
  __shared__ float EPT[5120];
  __shared__ int   TG[1024];

  const int lane = (int)threadIdx.x;
  const int b = (int)blockIdx.x;

  #pragma unroll
  for (int k = 0; k < 80; ++k) EPT[lane + 64 * k] = 0.0f;
  #pragma unroll
  for (int k = 0; k < 16; ++k) {
    const int lc = lane + 64 * k;
    int vv = 4 << 10;
    if (lc >= 256 && lc < 768) vv = (tgt[b * 512 + (lc - 256)] << 10);
    TG[((lc & 7) << 7) + (lc >> 3)] = vv;
  }
  #pragma unroll
  for (int k = 0; k < 8; ++k) {
    const int a = lane + 64 * k;
    const float4 v = ((const float4*)pred)[b * 512 + a];
    const int base = ((a & 7) << 7) + 32 + (a >> 3);
    EPT[base]        = __expf(v.x);
    EPT[1024 + base] = __expf(v.y);
    EPT[2048 + base] = __expf(v.z);
    EPT[3072 + base] = __expf(v.w);
  }
  __syncthreads();

  int PE_[8], PO_[8];
  float A[8], R[8], D[8], SE[8], SO[8];
  #pragma unroll
  for (int s = 0; s < 8; ++s) {
    const int j = 8 * lane + s;
    const int pe1 = 255 + j, pe2 = 765 - j;
    PE_[s] = pe1 < pe2 ? pe1 : pe2;
    const int po2 = 764 - j;
    PO_[s] = pe1 < po2 ? pe1 : po2;
    A[s] = R[s] = D[s] = 0.0f;
    SE[s] = SO[s] = 0.0f;
  }
  float ac0 = 0.0f, ac1 = 0.0f, ac2 = 0.0f, ac3 = 0.0f;
  float one = 1.0f;
  int Etot = 0;
  const int lanem1 = (lane + 63) & 63;
  const int lanep1 = (lane + 1) & 63;
  const bool is0 = (lane == 0);
  const bool is63 = (lane == 63);

  int tgO[8], tgE0[8];
  float esE[8], esO[8];
  #pragma unroll
  for (int s = 0; s < 8; ++s) {
    tgE0[s] = TG[lane + (((s + 1) & 7) << 7) + ((s + 1) >> 3)];
    tgO[s]  = TG[lane + (((s + 2) & 7) << 7) + ((s + 2) >> 3)];
  }
  #pragma unroll
  for (int s = 0; s < 8; ++s) {
    esE[s] = EPT[tgE0[s] + (63 - lane) + ((7 - s) << 7)];
    esO[s] = EPT[tgO[s]  + (63 - lane) + ((7 - s) << 7)];
  }

  int esWb = 63 - lane;
  int tgWb = lane;
  float mcar = 0.0f;

  for (int b2 = 0; b2 < 64; ++b2) {
    #pragma unroll
    for (int t = 0; t < 8; ++t) {
      const int p = (b2 << 3) + t;
      const int pm1 = p - 1;

      int tgN[8];
      #pragma unroll
      for (int s = 0; s < 8; ++s)
        tgN[s] = TG[tgWb + (((s + 3 + t) & 7) << 7) + ((s + 3 + t) >> 3)];

      const float rc7 = A[7] * EGO + R[7] * EGE;
      float rcs = __shfl(rc7, lanem1, 64);
      float esEn[8];
      #pragma unroll
      for (int ss = 0; ss < 8; ++ss) {
        const int s = 7 - ss;
        float right;
        if (s == 0) right = is0 ? 0.0f : rcs;
        else        right = A[s - 1] * EGO + R[s - 1] * EGE;
        const float dn = (A[s] + R[s]) * EGO + D[s] * EGE;
        const bool val  = (p   <= PE_[s]);
        const bool valS = (pm1 <= PE_[s]);
        const float esg = val ? esE[s] : 0.0f;
        const float al  = esg * (SE[s] + one);
        const float pav = valS ? SE[s] : 0.0f;
        const float pa  = pav * esE[s];
        if ((s & 3) == 0) ac0 += pa; else if ((s & 3) == 1) ac1 += pa;
        else if ((s & 3) == 2) ac2 += pa; else ac3 += pa;
        const float s3 = al + right + dn;
        SE[s] = s3;
        A[s] = al; R[s] = right; D[s] = dn;
        esEn[s] = EPT[tgO[s] + esWb + (((7 - s + t + 1) & 7) << 7) + ((7 - s + t + 1) >> 3)];
      }

      const float uc0 = (A[0] + R[0]) * EGO + D[0] * EGE;
      float ucs = __shfl(uc0, lanep1, 64);
      #pragma unroll
      for (int s = 0; s < 8; ++s) {
        float dnv;
        if (s == 7) dnv = is63 ? 0.0f : ucs;
        else {
          dnv = (A[s + 1] + R[s + 1]) * EGO + D[s + 1] * EGE;
          if (s == 6) dnv = is63 ? 0.0f : dnv;
        }
        const float rt = A[s] * EGO + R[s] * EGE;
        const bool val  = (p   <= PO_[s]);
        const bool valS = (pm1 <= PO_[s]);
        const float esg = val ? esO[s] : 0.0f;
        const float al  = esg * (SO[s] + one);
        const float pav = valS ? SO[s] : 0.0f;
        const float pa  = pav * esO[s];
        if ((s & 3) == 0) ac0 += pa; else if ((s & 3) == 1) ac1 += pa;
        else if ((s & 3) == 2) ac2 += pa; else ac3 += pa;
        const float s3 = al + rt + dnv;
        SO[s] = s3;
        A[s] = al; R[s] = rt; D[s] = dnv;
      }

      float esOn[8];
      #pragma unroll
      for (int s = 0; s < 8; ++s)
        esOn[s] = EPT[tgN[s] + esWb + (((7 - s + t + 1) & 7) << 7) + ((7 - s + t + 1) >> 3)];

      #pragma unroll
      for (int s = 0; s < 8; ++s) { tgO[s] = tgN[s]; esE[s] = esEn[s]; esO[s] = esOn[s]; }
    }
    ++esWb; ++tgWb;

    if ((b2 & 1) == 0) {
      float mx = fmaxf(SE[0], SO[0]);
      #pragma unroll
      for (int s = 1; s < 8; ++s) mx = fmaxf(mx, fmaxf(SE[s], SO[s]));
      mx = fmaxf(mx, __shfl_xor(mx, 1, 64));
      mx = fmaxf(mx, __shfl_xor(mx, 2, 64));
      mx = fmaxf(mx, __shfl_xor(mx, 4, 64));
      mcar = mx;
    } else {
      float mx = mcar;
      mx = fmaxf(mx, __shfl_xor(mx, 8, 64));
      mx = fmaxf(mx, __shfl_xor(mx, 16, 64));
      mx = fmaxf(mx, __shfl_xor(mx, 32, 64));
      const int ex = (int)((__float_as_uint(mx) >> 23) & 0xff);
      const float sc = __uint_as_float((unsigned)(253 - ex) << 23);
      Etot += ex - 126;
      #pragma unroll
      for (int s = 0; s < 8; ++s) {
        A[s] *= sc; R[s] *= sc; D[s] *= sc; SE[s] *= sc; SO[s] *= sc;
      }
      ac0 *= sc; ac1 *= sc; ac2 *= sc; ac3 *= sc;
      one *= sc;
    }
  }

  float atot = (ac0 + ac1) + (ac2 + ac3);
  #pragma unroll
  for (int off = 1; off < 64; off <<= 1) atot += __shfl_xor(atot, off, 64);
  if (lane == 0) partials[b] = __logf(atot) + (float)Etot * 0.69314718055994531f;
}

__global__ void sw_reduce_kernel(const float* __restrict__ partials, float* __restrict__ out) {
  const int t = (int)threadIdx.x;
  float v = (t < 32) ? partials[t] : 0.0f;
  for (int off = 32; off; off >>= 1) v += __shfl_down(v, off, 64);
  if (t == 0) out[0] = -v * (1.0f / 32.0f);
}

extern "C" void kernel_launch(void* const* d_in, const int* in_sizes, int n_in,
                              void* d_out, int out_size, void* d_ws, size_t ws_size,
                              hipStream_t stream) {
  const float* pred = (const float*)d_in[0];   // (32, 512, 4) fp32
  const int*   tgt  = (const int*)d_in[1];     // (32, 512) int32
  float* partials = (float*)d_ws;              // 32 floats at offset 0
  float* out = (float*)d_out;                  // scalar

  // X = 64 MiB at offset 1024, + 1 KiB guard for halo vf2 over/under-reads.
  if (ws_size >= (size_t)67110912ULL) {
    float* X = (float*)((char*)d_ws + 1024);
    sw_pre_kernel<<<16384, 512, 0, stream>>>(pred, tgt, X);
    sw_dp_fast<<<32, 512, 0, stream>>>(X, partials);
  } else {
    sw_dp_kernel<<<32, 64, 0, stream>>>(pred, tgt, partials);
  }
  sw_reduce_kernel<<<1, 64, 0, stream>>>(partials, out);
}

// Round 15
// 126.600 us; speedup vs baseline: 1.0728x; 1.0728x over previous
//
#include <hip/hip_runtime.h>

#define EGO 0.018315638888734179f   // exp(-4)
#define EGE 0.36787944117144233f    // exp(-1)

typedef float vf2 __attribute__((ext_vector_type(2)));

__device__ __forceinline__ vf2 pk_fma(vf2 a, vf2 b, vf2 c) {
  vf2 d; asm("v_pk_fma_f32 %0, %1, %2, %3" : "=v"(d) : "v"(a), "v"(b), "v"(c)); return d;
}
__device__ __forceinline__ vf2 pk_add(vf2 a, vf2 b) {
  vf2 d; asm("v_pk_add_f32 %0, %1, %2" : "=v"(d) : "v"(a), "v"(b)); return d;
}
__device__ __forceinline__ vf2 pk_mul(vf2 a, vf2 b) {
  vf2 d; asm("v_pk_mul_f32 %0, %1, %2" : "=v"(d) : "v"(a), "v"(b)); return d;
}

// DPP wave-wide shifts (GFX9/CDNA): VALU latency, no LDS pipe.
__device__ __forceinline__ float dpp_shr1(float x) {
  return __int_as_float(__builtin_amdgcn_update_dpp(
      0, __float_as_int(x), 0x138, 0xf, 0xf, true));
}
__device__ __forceinline__ float dpp_shl1(float x) {
  return __int_as_float(__builtin_amdgcn_update_dpp(
      0, __float_as_int(x), 0x130, 0xf, 0xf, true));
}

__device__ __forceinline__ float escale(int k) {   // 2^k, clamped to normal range
  k = k < -126 ? -126 : (k > 127 ? 127 : k);
  return __uint_as_float((unsigned)(k + 127) << 23);
}

// =====================================================================
// Precompute diag-major gathered exp(scores), fp32:
// X[((b*512+p)*2+half)*512 + j]. Batch b's blocks land on XCD b%8.
// =====================================================================
__global__ __launch_bounds__(512) void sw_pre_kernel(const float* __restrict__ pred,
                                                     const int* __restrict__ tgt,
                                                     float* __restrict__ X) {
  const int q = (int)blockIdx.x;
  const int b = (q & 7) | ((q >> 12) << 3);   // b%8 == q%8 -> XCD affinity
  const int p = (q >> 3) & 511;
  const int j = (int)threadIdx.x;
  const int a = 255 - j + p;
  const int c = p + j - 255;
  const bool av = (a >= 0) && (a < 512);
  float evn = 0.0f, odd = 0.0f;
  if (av && c >= 0 && c < 512)
    evn = __expf(pred[(((b << 9) + a) << 2) + tgt[(b << 9) + c]]);
  if (av && (c + 1) >= 0 && (c + 1) < 512)
    odd = __expf(pred[(((b << 9) + a) << 2) + tgt[(b << 9) + c + 1]]);
  float* base = X + (((size_t)((b << 9) | p)) << 10);
  base[j] = evn;
  base[512 + j] = odd;
}

// =====================================================================
// DP with halo: one batch/block, 8 waves, 2 slots/lane, packed fp32 math,
// DPP lane shifts. vs R14: X prefetch deepened 4 -> 8 buffers so the
// ~900cy HBM latency on the ~50% of X that misses L2 (FETCH=32.8MB) is
// fully covered (issue-to-consume ~8 iters ~ 1000+cy).
// =====================================================================
__global__ __launch_bounds__(512) void sw_dp_fast(const float* __restrict__ X,
                                                  float* __restrict__ partials) {
  __shared__ float SLDS[5 * 512];
  __shared__ float MXl[8], SUMl[8];
  __shared__ int   ETl[8], ETf[8];

  const int tid = (int)threadIdx.x;
  const int w = tid >> 6, lane = tid & 63;
  const int b = (int)blockIdx.x;
  const float* Xb = X + ((size_t)b << 19);
  const int jld = 64 * w - 32 + 2 * lane;

  int jj[2], PEes[2], POes[2];
  bool wrS[2], rdh[2], phh[2], owS[2];
  #pragma unroll
  for (int s = 0; s < 2; ++s) {
    const int j = jld + s;
    jj[s] = j;
    const bool vj = (j >= 0) && (j < 512);
    const int pe = (255 + j < 765 - j) ? 255 + j : 765 - j;
    const int po = (255 + j < 764 - j) ? 255 + j : 764 - j;
    PEes[s] = vj ? pe : -1;        // phantom slots: always gated off
    POes[s] = vj ? po : -1;
    owS[s] = (j >= 64 * w) && (j < 64 * w + 64);
    const int idx = 2 * lane + s;
    wrS[s] = (idx >= 32) && (idx < 96);
    const bool halo = (idx < 32) || (idx >= 96);
    rdh[s] = halo && vj;
    phh[s] = halo && !vj;
  }
  const bool isPh1 = (jj[1] == 511);    // wave 7, lane 47: kill its DC

  const vf2 EGOP = {EGO, EGO};
  const vf2 EGEP = {EGE, EGE};
  vf2 U = {0,0}, Dd = {0,0}, RC = {0,0}, SE = {0,0}, SO = {0,0}, acc = {0,0};
  vf2 oneP = {1.0f, 1.0f};
  int EtotW = 0;

  vf2 evb[8], odb[8];

#define LOADP(par, p) do {                                                    \
    const float* row_ = Xb + (((size_t)(p)) << 10);                           \
    evb[par] = *(const vf2*)(row_ + jld);                                     \
    odb[par] = *(const vf2*)(row_ + 512 + jld);                               \
  } while (0)

#define SYNC() do {                                                           \
    asm volatile("s_waitcnt lgkmcnt(0)" ::: "memory");                        \
    __builtin_amdgcn_s_barrier();                                             \
    asm volatile("" ::: "memory");                                            \
  } while (0)

#define ITER(par, nxt, p) do {                                                \
    /* ---- even substep (d=2p): right from slot-1 ---- */                    \
    const float rcS_ = dpp_shr1(RC.y);                                        \
    vf2 rightP; rightP.x = rcS_; rightP.y = RC.x;                             \
    vf2 dnP = pk_fma(U, EGOP, pk_mul(Dd, EGEP));                              \
    vf2 SEone = pk_add(SE, oneP);                                             \
    vf2 esgP;                                                                 \
    esgP.x = ((p) <= PEes[0]) ? evb[par].x : 0.0f;                            \
    esgP.y = ((p) <= PEes[1]) ? evb[par].y : 0.0f;                            \
    vf2 alP = pk_mul(esgP, SEone);                                            \
    vf2 UnP = pk_add(alP, rightP);                                            \
    vf2 s3P = pk_add(UnP, dnP);                                               \
    acc = pk_fma(s3P, evb[nxt], acc);                                         \
    SE = s3P;                                                                 \
    vf2 DCt = pk_fma(UnP, EGOP, pk_mul(dnP, EGEP));                           \
    if (isPh1) DCt.y = 0.0f;   /* slot 511 phantom must not leak */           \
    vf2 RCe = pk_fma(alP, EGOP, pk_mul(rightP, EGEP));                        \
    /* ---- odd substep (d=2p+1): down from slot+1 ---- */                    \
    const float dcS_ = dpp_shl1(DCt.x);                                       \
    vf2 dnvP; dnvP.x = DCt.y; dnvP.y = dcS_;                                  \
    vf2 SOone = pk_add(SO, oneP);                                             \
    vf2 esgO;                                                                 \
    esgO.x = ((p) <= POes[0]) ? odb[par].x : 0.0f;                            \
    esgO.y = ((p) <= POes[1]) ? odb[par].y : 0.0f;                            \
    vf2 alO = pk_mul(esgO, SOone);                                            \
    vf2 UnO = pk_add(alO, RCe);                                               \
    vf2 s3O = pk_add(UnO, dnvP);                                              \
    acc = pk_fma(s3O, odb[nxt], acc);                                         \
    SO = s3O;                                                                 \
    RC = pk_fma(alO, EGOP, pk_mul(RCe, EGEP));                                \
    U = UnO; Dd = dnvP;                                                       \
  } while (0)

#define SOLO() do {                                                           \
    float mxl = fmaxf(fmaxf(SE.x, SO.x), fmaxf(SE.y, SO.y));                  \
    _Pragma("unroll")                                                         \
    for (int off = 1; off < 64; off <<= 1) mxl = fmaxf(mxl, __shfl_xor(mxl, off, 64)); \
    const int ex = (int)((__float_as_uint(mxl) >> 23) & 0xff);                \
    if (ex > 0) {                                                             \
      const float sc = __uint_as_float((unsigned)(253 - ex) << 23);           \
      EtotW += ex - 126;                                                      \
      vf2 scP = {sc, sc};                                                     \
      U = pk_mul(U, scP); Dd = pk_mul(Dd, scP); RC = pk_mul(RC, scP);         \
      SE = pk_mul(SE, scP); SO = pk_mul(SO, scP); acc = pk_mul(acc, scP);     \
      oneP = pk_mul(oneP, scP);                                               \
    }                                                                         \
  } while (0)

#define REFRESH() do {                                                        \
    float mxl = fmaxf(owS[0] ? fmaxf(SE.x, SO.x) : 0.0f,                      \
                      owS[1] ? fmaxf(SE.y, SO.y) : 0.0f);                     \
    _Pragma("unroll")                                                         \
    for (int off = 1; off < 64; off <<= 1) mxl = fmaxf(mxl, __shfl_xor(mxl, off, 64)); \
    if (lane == 0) { MXl[w] = mxl; ETl[w] = EtotW; }                          \
    if (wrS[0]) {                                                             \
      SLDS[jj[0]] = U.x; SLDS[512 + jj[0]] = Dd.x; SLDS[1024 + jj[0]] = RC.x; \
      SLDS[1536 + jj[0]] = SE.x; SLDS[2048 + jj[0]] = SO.x;                   \
    }                                                                         \
    if (wrS[1]) {                                                             \
      SLDS[jj[1]] = U.y; SLDS[512 + jj[1]] = Dd.y; SLDS[1024 + jj[1]] = RC.y; \
      SLDS[1536 + jj[1]] = SE.y; SLDS[2048 + jj[1]] = SO.y;                   \
    }                                                                         \
    SYNC();                                                                   \
    int ets_[8]; float mxs_[8];                                               \
    _Pragma("unroll")                                                         \
    for (int q2 = 0; q2 < 8; ++q2) { mxs_[q2] = MXl[q2]; ets_[q2] = ETl[q2]; }\
    int tn_ = -2147483647;                                                    \
    _Pragma("unroll")                                                         \
    for (int q2 = 0; q2 < 8; ++q2) {                                          \
      if (mxs_[q2] > 0.0f) {                                                  \
        const int t2_ = ets_[q2] + (int)((__float_as_uint(mxs_[q2]) >> 23) & 0xff) - 126; \
        if (t2_ > tn_) tn_ = t2_;                                             \
      }                                                                       \
    }                                                                         \
    if (tn_ == -2147483647) tn_ = EtotW;                                      \
    { const int dd_ = EtotW - tn_;                                            \
      const float ff_ = escale(dd_ - dd_ / 2) * escale(dd_ / 2);              \
      vf2 fP = {ff_, ff_};                                                    \
      U = pk_mul(U, fP); Dd = pk_mul(Dd, fP); RC = pk_mul(RC, fP);            \
      SE = pk_mul(SE, fP); SO = pk_mul(SO, fP); acc = pk_mul(acc, fP);        \
      oneP = pk_mul(oneP, fP); EtotW = tn_;                                   \
    }                                                                         \
    if (rdh[0]) {                                                             \
      const int oww_ = (2 * lane < 32) ? (w - 1) : (w + 1);                   \
      const int dd2_ = ets_[oww_] - EtotW;                                    \
      const float g_ = escale(dd2_ - dd2_ / 2) * escale(dd2_ / 2);            \
      U.x = SLDS[jj[0]] * g_; Dd.x = SLDS[512 + jj[0]] * g_;                  \
      RC.x = SLDS[1024 + jj[0]] * g_; SE.x = SLDS[1536 + jj[0]] * g_;         \
      SO.x = SLDS[2048 + jj[0]] * g_;                                         \
    } else if (phh[0]) { U.x = Dd.x = RC.x = SE.x = SO.x = 0.0f; }            \
    if (rdh[1]) {                                                             \
      const int oww_ = (2 * lane + 1 < 32) ? (w - 1) : (w + 1);               \
      const int dd2_ = ets_[oww_] - EtotW;                                    \
      const float g_ = escale(dd2_ - dd2_ / 2) * escale(dd2_ / 2);            \
      U.y = SLDS[jj[1]] * g_; Dd.y = SLDS[512 + jj[1]] * g_;                  \
      RC.y = SLDS[1024 + jj[1]] * g_; SE.y = SLDS[1536 + jj[1]] * g_;         \
      SO.y = SLDS[2048 + jj[1]] * g_;                                         \
    } else if (phh[1]) { U.y = Dd.y = RC.y = SE.y = SO.y = 0.0f; }            \
    SYNC();                                                                   \
  } while (0)

  LOADP(0, 0); LOADP(1, 1); LOADP(2, 2); LOADP(3, 3);
  LOADP(4, 4); LOADP(5, 5); LOADP(6, 6); LOADP(7, 7);

  for (int qq = 0; qq < 63; ++qq) {
    const int p0 = qq << 3;
    ITER(0, 1, p0);     LOADP(0, p0 + 8);
    ITER(1, 2, p0 + 1); LOADP(1, p0 + 9);
    ITER(2, 3, p0 + 2); LOADP(2, p0 + 10);
    ITER(3, 4, p0 + 3); LOADP(3, p0 + 11);
    ITER(4, 5, p0 + 4); LOADP(4, p0 + 12);
    ITER(5, 6, p0 + 5); LOADP(5, p0 + 13);
    ITER(6, 7, p0 + 6); LOADP(6, p0 + 14);
    ITER(7, 0, p0 + 7); LOADP(7, p0 + 15);
    const int ph = qq & 3;
    if (ph == 1) SOLO();          // after 16, 48, ... iters
    else if (ph == 3) REFRESH();  // after 32, 64, ... iters
  }
  // tail: p = 504..510 (buffers hold 504..511; rawn chain reads 505..511)
  ITER(0, 1, 504); ITER(1, 2, 505); ITER(2, 3, 506); ITER(3, 4, 507);
  ITER(4, 5, 508); ITER(5, 6, 509); ITER(6, 7, 510);

  // owned-slot acc only (halo slots computed real values redundantly)
  float atot = (owS[0] ? acc.x : 0.0f) + (owS[1] ? acc.y : 0.0f);
  #pragma unroll
  for (int off = 1; off < 64; off <<= 1) atot += __shfl_xor(atot, off, 64);
  if (lane == 0) { SUMl[w] = atot; ETf[w] = EtotW; }
  __syncthreads();
  if (tid == 0) {
    int M = ETf[0];
    for (int q2 = 1; q2 < 8; ++q2) if (ETf[q2] > M) M = ETf[q2];
    float T = 0.0f;
    for (int q2 = 0; q2 < 8; ++q2) T += SUMl[q2] * escale(ETf[q2] - M);
    partials[b] = __logf(T) + (float)M * 0.69314718055994531f;
  }

#undef LOADP
#undef SYNC
#undef ITER
#undef SOLO
#undef REFRESH
}

// =====================================================================
// Fallback (R3, validated absmax 0.0): used when ws_size is too small.
// =====================================================================
__global__ __launch_bounds__(64) void sw_dp_kernel(const float* __restrict__ pred,
                                                   const int* __restrict__ tgt,
                                                   float* __restrict__ partials) {
  __shared__ float EPT[5120];
  __shared__ int   TG[1024];

  const int lane = (int)threadIdx.x;
  const int b = (int)blockIdx.x;

  #pragma unroll
  for (int k = 0; k < 80; ++k) EPT[lane + 64 * k] = 0.0f;
  #pragma unroll
  for (int k = 0; k < 16; ++k) {
    const int lc = lane + 64 * k;
    int vv = 4 << 10;
    if (lc >= 256 && lc < 768) vv = (tgt[b * 512 + (lc - 256)] << 10);
    TG[((lc & 7) << 7) + (lc >> 3)] = vv;
  }
  #pragma unroll
  for (int k = 0; k < 8; ++k) {
    const int a = lane + 64 * k;
    const float4 v = ((const float4*)pred)[b * 512 + a];
    const int base = ((a & 7) << 7) + 32 + (a >> 3);
    EPT[base]        = __expf(v.x);
    EPT[1024 + base] = __expf(v.y);
    EPT[2048 + base] = __expf(v.z);
    EPT[3072 + base] = __expf(v.w);
  }
  __syncthreads();

  int PE_[8], PO_[8];
  float A[8], R[8], D[8], SE[8], SO[8];
  #pragma unroll
  for (int s = 0; s < 8; ++s) {
    const int j = 8 * lane + s;
    const int pe1 = 255 + j, pe2 = 765 - j;
    PE_[s] = pe1 < pe2 ? pe1 : pe2;
    const int po2 = 764 - j;
    PO_[s] = pe1 < po2 ? pe1 : po2;
    A[s] = R[s] = D[s] = 0.0f;
    SE[s] = SO[s] = 0.0f;
  }
  float ac0 = 0.0f, ac1 = 0.0f, ac2 = 0.0f, ac3 = 0.0f;
  float one = 1.0f;
  int Etot = 0;
  const int lanem1 = (lane + 63) & 63;
  const int lanep1 = (lane + 1) & 63;
  const bool is0 = (lane == 0);
  const bool is63 = (lane == 63);

  int tgO[8], tgE0[8];
  float esE[8], esO[8];
  #pragma unroll
  for (int s = 0; s < 8; ++s) {
    tgE0[s] = TG[lane + (((s + 1) & 7) << 7) + ((s + 1) >> 3)];
    tgO[s]  = TG[lane + (((s + 2) & 7) << 7) + ((s + 2) >> 3)];
  }
  #pragma unroll
  for (int s = 0; s < 8; ++s) {
    esE[s] = EPT[tgE0[s] + (63 - lane) + ((7 - s) << 7)];
    esO[s] = EPT[tgO[s]  + (63 - lane) + ((7 - s) << 7)];
  }

  int esWb = 63 - lane;
  int tgWb = lane;
  float mcar = 0.0f;

  for (int b2 = 0; b2 < 64; ++b2) {
    #pragma unroll
    for (int t = 0; t < 8; ++t) {
      const int p = (b2 << 3) + t;
      const int pm1 = p - 1;

      int tgN[8];
      #pragma unroll
      for (int s = 0; s < 8; ++s)
        tgN[s] = TG[tgWb + (((s + 3 + t) & 7) << 7) + ((s + 3 + t) >> 3)];

      const float rc7 = A[7] * EGO + R[7] * EGE;
      float rcs = __shfl(rc7, lanem1, 64);
      float esEn[8];
      #pragma unroll
      for (int ss = 0; ss < 8; ++ss) {
        const int s = 7 - ss;
        float right;
        if (s == 0) right = is0 ? 0.0f : rcs;
        else        right = A[s - 1] * EGO + R[s - 1] * EGE;
        const float dn = (A[s] + R[s]) * EGO + D[s] * EGE;
        const bool val  = (p   <= PE_[s]);
        const bool valS = (pm1 <= PE_[s]);
        const float esg = val ? esE[s] : 0.0f;
        const float al  = esg * (SE[s] + one);
        const float pav = valS ? SE[s] : 0.0f;
        const float pa  = pav * esE[s];
        if ((s & 3) == 0) ac0 += pa; else if ((s & 3) == 1) ac1 += pa;
        else if ((s & 3) == 2) ac2 += pa; else ac3 += pa;
        const float s3 = al + right + dn;
        SE[s] = s3;
        A[s] = al; R[s] = right; D[s] = dn;
        esEn[s] = EPT[tgO[s] + esWb + (((7 - s + t + 1) & 7) << 7) + ((7 - s + t + 1) >> 3)];
      }

      const float uc0 = (A[0] + R[0]) * EGO + D[0] * EGE;
      float ucs = __shfl(uc0, lanep1, 64);
      #pragma unroll
      for (int s = 0; s < 8; ++s) {
        float dnv;
        if (s == 7) dnv = is63 ? 0.0f : ucs;
        else {
          dnv = (A[s + 1] + R[s + 1]) * EGO + D[s + 1] * EGE;
          if (s == 6) dnv = is63 ? 0.0f : dnv;
        }
        const float rt = A[s] * EGO + R[s] * EGE;
        const bool val  = (p   <= PO_[s]);
        const bool valS = (pm1 <= PO_[s]);
        const float esg = val ? esO[s] : 0.0f;
        const float al  = esg * (SO[s] + one);
        const float pav = valS ? SO[s] : 0.0f;
        const float pa  = pav * esO[s];
        if ((s & 3) == 0) ac0 += pa; else if ((s & 3) == 1) ac1 += pa;
        else if ((s & 3) == 2) ac2 += pa; else ac3 += pa;
        const float s3 = al + rt + dnv;
        SO[s] = s3;
        A[s] = al; R[s] = rt; D[s] = dnv;
      }

      float esOn[8];
      #pragma unroll
      for (int s = 0; s < 8; ++s)
        esOn[s] = EPT[tgN[s] + esWb + (((7 - s + t + 1) & 7) << 7) + ((7 - s + t + 1) >> 3)];

      #pragma unroll
      for (int s = 0; s < 8; ++s) { tgO[s] = tgN[s]; esE[s] = esEn[s]; esO[s] = esOn[s]; }
    }
    ++esWb; ++tgWb;

    if ((b2 & 1) == 0) {
      float mx = fmaxf(SE[0], SO[0]);
      #pragma unroll
      for (int s = 1; s < 8; ++s) mx = fmaxf(mx, fmaxf(SE[s], SO[s]));
      mx = fmaxf(mx, __shfl_xor(mx, 1, 64));
      mx = fmaxf(mx, __shfl_xor(mx, 2, 64));
      mx = fmaxf(mx, __shfl_xor(mx, 4, 64));
      mcar = mx;
    } else {
      float mx = mcar;
      mx = fmaxf(mx, __shfl_xor(mx, 8, 64));
      mx = fmaxf(mx, __shfl_xor(mx, 16, 64));
      mx = fmaxf(mx, __shfl_xor(mx, 32, 64));
      const int ex = (int)((__float_as_uint(mx) >> 23) & 0xff);
      const float sc = __uint_as_float((unsigned)(253 - ex) << 23);
      Etot += ex - 126;
      #pragma unroll
      for (int s = 0; s < 8; ++s) {
        A[s] *= sc; R[s] *= sc; D[s] *= sc; SE[s] *= sc; SO[s] *= sc;
      }
      ac0 *= sc; ac1 *= sc; ac2 *= sc; ac3 *= sc;
      one *= sc;
    }
  }

  float atot = (ac0 + ac1) + (ac2 + ac3);
  #pragma unroll
  for (int off = 1; off < 64; off <<= 1) atot += __shfl_xor(atot, off, 64);
  if (lane == 0) partials[b] = __logf(atot) + (float)Etot * 0.69314718055994531f;
}

__global__ void sw_reduce_kernel(const float* __restrict__ partials, float* __restrict__ out) {
  const int t = (int)threadIdx.x;
  float v = (t < 32) ? partials[t] : 0.0f;
  for (int off = 32; off; off >>= 1) v += __shfl_down(v, off, 64);
  if (t == 0) out[0] = -v * (1.0f / 32.0f);
}

extern "C" void kernel_launch(void* const* d_in, const int* in_sizes, int n_in,
                              void* d_out, int out_size, void* d_ws, size_t ws_size,
                              hipStream_t stream) {
  const float* pred = (const float*)d_in[0];   // (32, 512, 4) fp32
  const int*   tgt  = (const int*)d_in[1];     // (32, 512) int32
  float* partials = (float*)d_ws;              // 32 floats at offset 0
  float* out = (float*)d_out;                  // scalar

  // X = 64 MiB at offset 1024, + 1 KiB guard for halo vf2 over/under-reads.
  if (ws_size >= (size_t)67110912ULL) {
    float* X = (float*)((char*)d_ws + 1024);
    sw_pre_kernel<<<16384, 512, 0, stream>>>(pred, tgt, X);
    sw_dp_fast<<<32, 512, 0, stream>>>(X, partials);
  } else {
    sw_dp_kernel<<<32, 64, 0, stream>>>(pred, tgt, partials);
  }
  sw_reduce_kernel<<<1, 64, 0, stream>>>(partials, out);
}